// Round 4
// baseline (951.741 us; speedup 1.0000x reference)
//
#include <hip/hip_runtime.h>

#define W_IMG 512
#define H_IMG 512
#define PLANES 96                  // 32 * 3
#define NPIX 25165824.0            // 96 * 512 * 512

#define SW 64                      // output cols per wave (strip)
#define SH 64                      // output rows per wave (band)
#define NROWS (SH + 10)            // 74 streamed input rows
#define NPAIR 38                   // staged col-pairs: cols [c0-6, c0+70)
#define WPB 4                      // waves per block
#define XS (W_IMG / SW)            // 8 strips
#define YB (H_IMG / SH)            // 8 bands
#define BLOCKS_PER_PLANE (XS * YB / WPB)   // 16

__global__ void ssim_zero(double* acc) {
    if (threadIdx.x == 0) acc[0] = 0.0;
}

__global__ void ssim_final(const double* __restrict__ acc, float* __restrict__ out) {
    if (threadIdx.x == 0) out[0] = (float)(1.0 - acc[0] / NPIX);
}

__global__ __launch_bounds__(256, 6)
void ssim_main(const float* __restrict__ img1,
               const float* __restrict__ img2,
               double* __restrict__ acc)
{
    // normalized 11-tap Gaussian, sigma=1.5 (matches reference _create_window)
    constexpr float G[11] = {
        0.00102838f, 0.00759875f, 0.03600077f, 0.10936070f, 0.21300540f,
        0.26601180f,
        0.21300540f, 0.10936070f, 0.03600077f, 0.00759875f, 0.00102838f };
    constexpr float C1 = 0.0001f;
    constexpr float C2 = 0.0009f;

    // per-wave private staging: one input row, double-buffered
    // pair p = cols {c0-6+2p, c0-5+2p} stored as {a0,b0,a1,b1}
    __shared__ __align__(16) float4 sbuf[WPB][2][NPAIR];
    __shared__ float wred[WPB];

    const int tid = threadIdx.x;
    const int wv  = tid >> 6;          // wave in block
    const int L   = tid & 63;          // lane
    const int wid = blockIdx.x * WPB + wv;   // 0..63 per plane
    const int c0  = (wid & (XS - 1)) * SW;
    const int r0  = (wid >> 3) * SH;
    const size_t pofs = (size_t)blockIdx.y * (H_IMG * W_IMG);
    const float* __restrict__ p1 = img1 + pofs;
    const float* __restrict__ p2 = img2 + pofs;

    // this lane's output column c = c0 + L; aligned 12-tap window
    const int lw  = (L + 1) & ~1;      // local even window start (staged-col units)
    const int p0  = (L + 1) >> 1;      // first staged pair of the window
    const bool odd = ((L + 1) & 1) == 0;   // window start (c-5) is odd <=> L even

    // parity-shifted 12-tap coefficient vector (8B-aligned reads, no selects)
    float Gp[12];
    Gp[0] = odd ? 0.f : G[0];
    #pragma unroll
    for (int j = 1; j <= 10; ++j) Gp[j] = odd ? G[j - 1] : G[j];
    Gp[11] = odd ? G[10] : 0.f;
    (void)lw;

    // staging: lane < 38 owns one col-pair
    const int gp = c0 - 6 + 2 * L;
    const bool sth = (L < NPAIR);
    const bool cok = sth && (gp >= 0) && (gp < W_IMG);   // pairs never straddle

    float2 ra = make_float2(0.f, 0.f), rb = ra;
    auto LOADROW = [&](int s) {
        ra = make_float2(0.f, 0.f); rb = ra;
        const int gr = r0 - 5 + s;
        if (cok && (unsigned)gr < (unsigned)H_IMG) {
            const int off = gr * W_IMG + gp;
            ra = *(const float2*)(p1 + off);
            rb = *(const float2*)(p2 + off);
        }
    };

    float ring[5][11];   // 5 maps x 11 pending H-conv rows, statically indexed
    float lsum = 0.f;

    // ---- prologue: stage row 0, prefetch row 1 (wave-private, no barriers) ----
    LOADROW(0);
    if (sth) sbuf[wv][0][L] = make_float4(ra.x, rb.x, ra.y, rb.y);
    LOADROW(1);

    int cur = 0;
    for (int sb = 0; sb < 77; sb += 11) {
        #pragma unroll
        for (int j = 0; j < 11; ++j) {
            const int s = sb + j;    // streamed row; ring slot = s % 11 = j

            // stage row s+1 (prefetched last iter) into the other buffer
            if (s + 1 < NROWS) {
                if (sth) sbuf[wv][cur ^ 1][L] = make_float4(ra.x, rb.x, ra.y, rb.y);
            }
            // prefetch row s+2 to registers
            if (s + 2 < NROWS) LOADROW(s + 2);

            // ---- horizontal 11-tap on row s -> push 5 ring values ----
            if (s < NROWS) {
                const float4 f0 = sbuf[wv][cur][p0 + 0];
                const float4 f1 = sbuf[wv][cur][p0 + 1];
                const float4 f2 = sbuf[wv][cur][p0 + 2];
                const float4 f3 = sbuf[wv][cur][p0 + 3];
                const float4 f4 = sbuf[wv][cur][p0 + 4];
                const float4 f5 = sbuf[wv][cur][p0 + 5];
                const float av[12] = { f0.x,f0.z, f1.x,f1.z, f2.x,f2.z,
                                       f3.x,f3.z, f4.x,f4.z, f5.x,f5.z };
                const float bv[12] = { f0.y,f0.w, f1.y,f1.w, f2.y,f2.w,
                                       f3.y,f3.w, f4.y,f4.w, f5.y,f5.w };
                float m1 = 0.f, m2 = 0.f, h11 = 0.f, h22 = 0.f, h12 = 0.f;
                #pragma unroll
                for (int q = 0; q < 12; ++q) {
                    const float t1 = Gp[q] * av[q];
                    const float t2 = Gp[q] * bv[q];
                    m1 += t1;  m2 += t2;
                    h11 = fmaf(t1, av[q], h11);
                    h22 = fmaf(t2, bv[q], h22);
                    h12 = fmaf(t1, bv[q], h12);
                }
                ring[0][j] = m1;  ring[1][j] = m2;
                ring[2][j] = h11; ring[3][j] = h22; ring[4][j] = h12;
            }

            // ---- vertical 11-tap + SSIM for output row s-10 ----
            if (s >= 10 && s < NROWS) {
                float M1 = 0.f, M2 = 0.f, E11 = 0.f, E22 = 0.f, E12 = 0.f;
                #pragma unroll
                for (int k = 0; k < 11; ++k) {
                    const int sl = (j + 1 + k) % 11;   // compile-time
                    M1  = fmaf(G[k], ring[0][sl], M1);
                    M2  = fmaf(G[k], ring[1][sl], M2);
                    E11 = fmaf(G[k], ring[2][sl], E11);
                    E22 = fmaf(G[k], ring[3][sl], E22);
                    E12 = fmaf(G[k], ring[4][sl], E12);
                }
                const float mu1s = M1 * M1, mu2s = M2 * M2, mu12 = M1 * M2;
                const float v11 = fmaxf(E11 - mu1s, 0.f);
                const float v22 = fmaxf(E22 - mu2s, 0.f);
                const float v12 = E12 - mu12;
                const float num = fmaf(2.f, mu12, C1) * fmaf(2.f, v12, C2);
                const float den = (mu1s + mu2s + C1) * (v11 + v22 + C2);
                lsum = fmaf(num, __builtin_amdgcn_rcpf(den), lsum);
            }

            cur ^= 1;
        }
    }

    // ---- wave reduce -> one barrier -> one atomic per block ----
    #pragma unroll
    for (int off = 32; off > 0; off >>= 1)
        lsum += __shfl_down(lsum, off, 64);
    if (L == 0) wred[wv] = lsum;
    __syncthreads();
    if (tid == 0)
        atomicAdd(acc, (double)(wred[0] + wred[1] + wred[2] + wred[3]));
}

extern "C" void kernel_launch(void* const* d_in, const int* in_sizes, int n_in,
                              void* d_out, int out_size, void* d_ws, size_t ws_size,
                              hipStream_t stream) {
    const float* img1 = (const float*)d_in[0];
    const float* img2 = (const float*)d_in[1];
    float* out  = (float*)d_out;
    double* acc = (double*)d_ws;

    ssim_zero<<<dim3(1), dim3(64), 0, stream>>>(acc);
    ssim_main<<<dim3(BLOCKS_PER_PLANE, PLANES), dim3(256), 0, stream>>>(img1, img2, acc);
    ssim_final<<<dim3(1), dim3(64), 0, stream>>>(acc, out);
}

// Round 5
// 122.357 us; speedup vs baseline: 7.7784x; 7.7784x over previous
//
#include <hip/hip_runtime.h>

#define W_IMG 512
#define H_IMG 512
#define PLANES 96                  // 32 * 3
#define NPIX 25165824.0            // 96 * 512 * 512

#define SW 64                      // output cols per wave (strip)
#define SH 64                      // output rows per wave (band)
#define NROWS (SH + 10)            // 74 streamed input rows
#define NPAIR 38                   // staged col-pairs: cols [c0-6, c0+70)
#define WPB 4                      // waves per block
#define XS (W_IMG / SW)            // 8 strips
#define YB (H_IMG / SH)            // 8 bands
#define BLOCKS_PER_PLANE (XS * YB / WPB)   // 16

__global__ void ssim_zero(double* acc) {
    if (threadIdx.x == 0) acc[0] = 0.0;
}

__global__ void ssim_final(const double* __restrict__ acc, float* __restrict__ out) {
    if (threadIdx.x == 0) out[0] = (float)(1.0 - acc[0] / NPIX);
}

// launch_bounds(256,2): VGPR cap 256. (256,6) in the previous round capped the
// allocator at ~85 and spilled the 55-reg ring to scratch (838 MB scratch
// writes, 9.6% VALUBusy). The ring MUST live in registers.
__global__ __launch_bounds__(256, 2)
void ssim_main(const float* __restrict__ img1,
               const float* __restrict__ img2,
               double* __restrict__ acc)
{
    // normalized 11-tap Gaussian, sigma=1.5 (matches reference _create_window)
    constexpr float G[11] = {
        0.00102838f, 0.00759875f, 0.03600077f, 0.10936070f, 0.21300540f,
        0.26601180f,
        0.21300540f, 0.10936070f, 0.03600077f, 0.00759875f, 0.00102838f };
    constexpr float C1 = 0.0001f;
    constexpr float C2 = 0.0009f;

    // per-wave private staging: one input row, double-buffered
    // pair p = cols {c0-6+2p, c0-5+2p} stored as {a0,b0,a1,b1}
    __shared__ __align__(16) float4 sbuf[WPB][2][NPAIR];
    __shared__ float wred[WPB];

    const int tid = threadIdx.x;
    const int wv  = tid >> 6;          // wave in block
    const int L   = tid & 63;          // lane
    const int wid = blockIdx.x * WPB + wv;   // 0..63 per plane
    const int c0  = (wid & (XS - 1)) * SW;
    const int r0  = (wid >> 3) * SH;
    const size_t pofs = (size_t)blockIdx.y * (H_IMG * W_IMG);
    const float* __restrict__ p1 = img1 + pofs;
    const float* __restrict__ p2 = img2 + pofs;

    // this lane's output column c = c0 + L; aligned 12-tap window
    const int p0  = (L + 1) >> 1;      // first staged pair of the window
    const bool odd = ((L + 1) & 1) == 0;   // window start (c-5) is odd <=> L even

    // parity-shifted 12-tap coefficient vector (8B-aligned reads, no selects;
    // lane-uniform booleans fold to cndmask on inline constants -> ~0 VGPRs)
    float Gp[12];
    Gp[0] = odd ? 0.f : G[0];
    #pragma unroll
    for (int j = 1; j <= 10; ++j) Gp[j] = odd ? G[j - 1] : G[j];
    Gp[11] = odd ? G[10] : 0.f;

    // staging: lane < 38 owns one col-pair
    const int gp = c0 - 6 + 2 * L;
    const bool sth = (L < NPAIR);
    const bool cok = sth && (gp >= 0) && (gp < W_IMG);   // pairs never straddle

    float2 ra = make_float2(0.f, 0.f), rb = ra;
    auto LOADROW = [&](int s) {
        ra = make_float2(0.f, 0.f); rb = ra;
        const int gr = r0 - 5 + s;
        if (cok && (unsigned)gr < (unsigned)H_IMG) {
            const int off = gr * W_IMG + gp;
            ra = *(const float2*)(p1 + off);
            rb = *(const float2*)(p2 + off);
        }
    };

    float ring[5][11];   // 5 maps x 11 pending H-conv rows, statically indexed
    float lsum = 0.f;

    // ---- prologue: stage row 0, prefetch row 1 (wave-private, no barriers) ----
    LOADROW(0);
    if (sth) sbuf[wv][0][L] = make_float4(ra.x, rb.x, ra.y, rb.y);
    LOADROW(1);

    int cur = 0;
    #pragma unroll 1
    for (int sb = 0; sb < 77; sb += 11) {
        #pragma unroll
        for (int j = 0; j < 11; ++j) {
            const int s = sb + j;    // streamed row; ring slot = s % 11 = j

            // stage row s+1 (prefetched last iter) into the other buffer
            if (s + 1 < NROWS) {
                if (sth) sbuf[wv][cur ^ 1][L] = make_float4(ra.x, rb.x, ra.y, rb.y);
            }
            // prefetch row s+2 to registers
            if (s + 2 < NROWS) LOADROW(s + 2);

            // ---- horizontal 11-tap on row s -> push 5 ring values ----
            if (s < NROWS) {
                const float4 f0 = sbuf[wv][cur][p0 + 0];
                const float4 f1 = sbuf[wv][cur][p0 + 1];
                const float4 f2 = sbuf[wv][cur][p0 + 2];
                const float4 f3 = sbuf[wv][cur][p0 + 3];
                const float4 f4 = sbuf[wv][cur][p0 + 4];
                const float4 f5 = sbuf[wv][cur][p0 + 5];
                const float av[12] = { f0.x,f0.z, f1.x,f1.z, f2.x,f2.z,
                                       f3.x,f3.z, f4.x,f4.z, f5.x,f5.z };
                const float bv[12] = { f0.y,f0.w, f1.y,f1.w, f2.y,f2.w,
                                       f3.y,f3.w, f4.y,f4.w, f5.y,f5.w };
                float m1 = 0.f, m2 = 0.f, h11 = 0.f, h22 = 0.f, h12 = 0.f;
                #pragma unroll
                for (int q = 0; q < 12; ++q) {
                    const float t1 = Gp[q] * av[q];
                    const float t2 = Gp[q] * bv[q];
                    m1 += t1;  m2 += t2;
                    h11 = fmaf(t1, av[q], h11);
                    h22 = fmaf(t2, bv[q], h22);
                    h12 = fmaf(t1, bv[q], h12);
                }
                ring[0][j] = m1;  ring[1][j] = m2;
                ring[2][j] = h11; ring[3][j] = h22; ring[4][j] = h12;
            }

            // ---- vertical 11-tap + SSIM for output row s-10 ----
            if (s >= 10 && s < NROWS) {
                float M1 = 0.f, M2 = 0.f, E11 = 0.f, E22 = 0.f, E12 = 0.f;
                #pragma unroll
                for (int k = 0; k < 11; ++k) {
                    const int sl = (j + 1 + k) % 11;   // compile-time
                    M1  = fmaf(G[k], ring[0][sl], M1);
                    M2  = fmaf(G[k], ring[1][sl], M2);
                    E11 = fmaf(G[k], ring[2][sl], E11);
                    E22 = fmaf(G[k], ring[3][sl], E22);
                    E12 = fmaf(G[k], ring[4][sl], E12);
                }
                const float mu1s = M1 * M1, mu2s = M2 * M2, mu12 = M1 * M2;
                const float v11 = fmaxf(E11 - mu1s, 0.f);
                const float v22 = fmaxf(E22 - mu2s, 0.f);
                const float v12 = E12 - mu12;
                const float num = fmaf(2.f, mu12, C1) * fmaf(2.f, v12, C2);
                const float den = (mu1s + mu2s + C1) * (v11 + v22 + C2);
                lsum = fmaf(num, __builtin_amdgcn_rcpf(den), lsum);
            }

            cur ^= 1;
        }
    }

    // ---- wave reduce -> one barrier -> one atomic per block ----
    #pragma unroll
    for (int off = 32; off > 0; off >>= 1)
        lsum += __shfl_down(lsum, off, 64);
    if (L == 0) wred[wv] = lsum;
    __syncthreads();
    if (tid == 0)
        atomicAdd(acc, (double)(wred[0] + wred[1] + wred[2] + wred[3]));
}

extern "C" void kernel_launch(void* const* d_in, const int* in_sizes, int n_in,
                              void* d_out, int out_size, void* d_ws, size_t ws_size,
                              hipStream_t stream) {
    const float* img1 = (const float*)d_in[0];
    const float* img2 = (const float*)d_in[1];
    float* out  = (float*)d_out;
    double* acc = (double*)d_ws;

    ssim_zero<<<dim3(1), dim3(64), 0, stream>>>(acc);
    ssim_main<<<dim3(BLOCKS_PER_PLANE, PLANES), dim3(256), 0, stream>>>(img1, img2, acc);
    ssim_final<<<dim3(1), dim3(64), 0, stream>>>(acc, out);
}